// Round 7
// baseline (144.149 us; speedup 1.0000x reference)
//
#include <hip/hip_runtime.h>
#include <math.h>

#define PW 256
#define PH 256
#define IW 4096
#define IH 2048
#define NB 64
#define PI_F 3.14159265358979323846f

// Compile-time permutation: 256 tile locations sorted by radius from output
// center. XCD k owns sorted slots [k*32, k*32+32) -> disjoint v-annulus of the
// equi band per XCD (view is pole-centered; equi row ~ f(radius)).
struct TilePerm {
    unsigned char t[256];
    constexpr TilePerm() : t{} {
        int r2[256] = {};
        for (int i = 0; i < 256; ++i) {
            int tx = i & 15, ty = i >> 4;
            int ddx = tx * 16 + 8 - 128, ddy = ty * 16 + 8 - 128;
            r2[i] = ddx * ddx + ddy * ddy;
            t[i] = (unsigned char)i;
        }
        for (int i = 1; i < 256; ++i) {
            unsigned char ti = t[i]; int ri = r2[i];
            int j = i - 1;
            while (j >= 0 && r2[j] > ri) { r2[j + 1] = r2[j]; t[j + 1] = t[j]; --j; }
            r2[j + 1] = ri; t[j + 1] = ti;
        }
    }
};
__device__ constexpr TilePerm kPerm{};

__device__ __forceinline__ float fast_tanh(float v) {
    // v in [0,1] here. 1 - 2/(e^{2v}+1). __fdividef -> v_rcp_f32 + mul.
    float e = __expf(2.0f * v);
    return 1.0f - __fdividef(2.0f, e + 1.0f);
}

__global__ __launch_bounds__(256) void e2p_kernel(
    const float* __restrict__ img,      // (3, IH, IW)
    const float* __restrict__ fov,      // (1,)
    const float* __restrict__ roll,     // (1,)
    const float* __restrict__ pitch,    // (1,)
    const float* __restrict__ yaw,      // (NB,)
    float* __restrict__ out)            // (NB, 3, PH, PW)
{
    // ---- grid decode: g -> (xcd slot, batch, radius-sorted tile) ----
    const int g    = blockIdx.x;        // 0..16383
    const int x8   = g & 7;             // heuristic XCD (dispatch round-robin)
    const int q    = g >> 3;
    const int b    = q & 63;            // batch innermost: 64 batches of one
    const int tsub = q >> 6;            // tile co-resident on one XCD
    const int tile = kPerm.t[x8 * 32 + tsub];
    const int tx   = tile & 15;
    const int ty   = tile >> 4;
    const int x    = tx * 16 + (threadIdx.x & 15);
    const int y    = ty * 16 + (threadIdx.x >> 4);

    __shared__ float P[11];   // r00..r22, f, 1/f
    if (threadIdx.x == 0) {
        float sr, cr, sp, cp, sy, cy;
        sincosf(roll[0], &sr, &cr);
        sincosf(pitch[0], &sp, &cp);
        sincosf(yaw[b], &sy, &cy);
        const float fovr = fov[0] * 0.017453292519943295f;   // deg2rad
        // R = Rz(yaw) @ Ry(pitch) @ Rx(roll)
        P[0] = cy * cp; P[1] = cy * sp * sr - sy * cr; P[2] = cy * sp * cr + sy * sr;
        P[3] = sy * cp; P[4] = sy * sp * sr + cy * cr; P[5] = sy * sp * cr - cy * sr;
        P[6] = -sp;     P[7] = cp * sr;                P[8] = cp * cr;
        float f = (float)PW / (2.0f * tanf(fovr * 0.5f));
        P[9] = f;
        P[10] = 1.0f / f;
    }
    __syncthreads();

    const float r00 = P[0], r01 = P[1], r02 = P[2];
    const float r10 = P[3], r11 = P[4], r12 = P[5];
    const float r20 = P[6], r21 = P[7], r22 = P[8];
    const float finv = P[10];

    const float dx = ((float)x - 128.0f) * finv;   // cx = PW/2
    const float dy = ((float)y - 128.0f) * finv;   // cy = PH/2

    const float d0 = r00 * dx + r01 * dy + r02;
    const float d1 = r10 * dx + r11 * dy + r12;
    const float d2 = r20 * dx + r21 * dy + r22;

    const float rn = rsqrtf(d0 * d0 + d1 * d1 + d2 * d2);
    float sa = d2 * rn;                          // clamp: approx can give |.|>1
    sa = fminf(1.0f, fmaxf(-1.0f, sa));
    const float phi = asinf(sa);
    const float theta = atan2f(d1, d0);

    // theta in (-pi, pi] -> raw u in (-4095.5, 0.5]; |raw| < W so fmod == id.
    float ui = (theta - PI_F) * ((float)IW / (2.0f * PI_F)) + 0.5f;
    if (ui < 0.0f) ui += (float)IW;
    // phi in [-pi/2, pi/2] -> raw v in [-2047.5, 0.5].
    float uj = (phi - 0.5f * PI_F) * ((float)IH / PI_F) + 0.5f;
    if (uj < 0.0f) uj += (float)IH;

    const float u0f = floorf(ui);
    const float v0f = floorf(uj);
    const float du = ui - u0f;
    const float dv = uj - v0f;

    int u0 = ((int)u0f) & (IW - 1);     // ui >= 0; handles ui==IW rounding edge too
    int u1 = (u0 + 1) & (IW - 1);
    int v0 = (int)v0f;
    if (v0 < 0) v0 = 0;
    if (v0 > IH - 1) v0 = IH - 1;
    int v1 = v0 + 1;
    if (v1 > IH - 1) v1 = IH - 1;

    const float w00 = (1.0f - du) * (1.0f - dv);
    const float w01 = du * (1.0f - dv);
    const float w10 = (1.0f - du) * dv;
    const float w11 = du * dv;

    const int i00 = v0 * IW + u0;
    const int i01 = v0 * IW + u1;
    const int i10 = v1 * IW + u0;
    const int i11 = v1 * IW + u1;

    float* o = out + ((size_t)(b * 3) * PH + y) * PW + x;
#pragma unroll
    for (int c = 0; c < 3; ++c) {
        const float* ic = img + (size_t)c * (IH * IW);
        float v = ic[i00] * w00 + ic[i01] * w01 + ic[i10] * w10 + ic[i11] * w11;
        o[(size_t)c * PH * PW] = fast_tanh(v);
    }
}

extern "C" void kernel_launch(void* const* d_in, const int* in_sizes, int n_in,
                              void* d_out, int out_size, void* d_ws, size_t ws_size,
                              hipStream_t stream) {
    const float* img   = (const float*)d_in[0];
    const float* fov   = (const float*)d_in[1];
    const float* roll  = (const float*)d_in[2];
    const float* pitch = (const float*)d_in[3];
    const float* yaw   = (const float*)d_in[4];
    float* out = (float*)d_out;

    e2p_kernel<<<NB * PH, 256, 0, stream>>>(img, fov, roll, pitch, yaw, out);
}

// Round 8
// 99.808 us; speedup vs baseline: 1.4443x; 1.4443x over previous
//
#include <hip/hip_runtime.h>
#include <math.h>

#define PW 256
#define PH 256
#define IW 4096
#define IH 2048
#define NB 64
#define PI_F 3.14159265358979323846f

// Compile-time permutation: 256 tile locations sorted by radius from output
// center. Radius ranks are dealt ROUND-ROBIN across XCDs (tile = perm[tsub*8+x8])
// so all 8 XCDs sweep inner->outer together: per-XCD work balanced (inner tiles
// are scatter-heavy, outer tiles dense), while the co-resident window on each
// XCD spans only ~32 radius ranks -> narrow v-band, L2-resident.
struct TilePerm {
    unsigned char t[256];
    constexpr TilePerm() : t{} {
        int r2[256] = {};
        for (int i = 0; i < 256; ++i) {
            int tx = i & 15, ty = i >> 4;
            int ddx = tx * 16 + 8 - 128, ddy = ty * 16 + 8 - 128;
            r2[i] = ddx * ddx + ddy * ddy;
            t[i] = (unsigned char)i;
        }
        for (int i = 1; i < 256; ++i) {
            unsigned char ti = t[i]; int ri = r2[i];
            int j = i - 1;
            while (j >= 0 && r2[j] > ri) { r2[j + 1] = r2[j]; t[j + 1] = t[j]; --j; }
            r2[j + 1] = ri; t[j + 1] = ti;
        }
    }
};
__device__ constexpr TilePerm kPerm{};

__device__ __forceinline__ float fast_tanh(float v) {
    // v in [0,1] here. 1 - 2/(e^{2v}+1). __fdividef -> v_rcp_f32 + mul.
    float e = __expf(2.0f * v);
    return 1.0f - __fdividef(2.0f, e + 1.0f);
}

__global__ __launch_bounds__(256) void e2p_kernel(
    const float* __restrict__ img,      // (3, IH, IW)
    const float* __restrict__ fov,      // (1,)
    const float* __restrict__ roll,     // (1,)
    const float* __restrict__ pitch,    // (1,)
    const float* __restrict__ yaw,      // (NB,)
    float* __restrict__ out)            // (NB, 3, PH, PW)
{
    // ---- grid decode: g -> (xcd, batch, radius-rank round-robin tile) ----
    const int g    = blockIdx.x;        // 0..16383
    const int x8   = g & 7;             // heuristic XCD (dispatch round-robin)
    const int q    = g >> 3;
    const int b    = q & 63;            // batch innermost: 64 batches co-resident
    const int tsub = q >> 6;            // radius-rank group
    const int tile = kPerm.t[tsub * 8 + x8];
    const int tx   = tile & 15;
    const int ty   = tile >> 4;
    const int x    = tx * 16 + (threadIdx.x & 15);
    const int y    = ty * 16 + (threadIdx.x >> 4);

    __shared__ float P[11];   // r00..r22, f, 1/f
    if (threadIdx.x == 0) {
        float sr, cr, sp, cp, sy, cy;
        sincosf(roll[0], &sr, &cr);
        sincosf(pitch[0], &sp, &cp);
        sincosf(yaw[b], &sy, &cy);
        const float fovr = fov[0] * 0.017453292519943295f;   // deg2rad
        // R = Rz(yaw) @ Ry(pitch) @ Rx(roll)
        P[0] = cy * cp; P[1] = cy * sp * sr - sy * cr; P[2] = cy * sp * cr + sy * sr;
        P[3] = sy * cp; P[4] = sy * sp * sr + cy * cr; P[5] = sy * sp * cr - cy * sr;
        P[6] = -sp;     P[7] = cp * sr;                P[8] = cp * cr;
        float f = (float)PW / (2.0f * tanf(fovr * 0.5f));
        P[9] = f;
        P[10] = 1.0f / f;
    }
    __syncthreads();

    const float r00 = P[0], r01 = P[1], r02 = P[2];
    const float r10 = P[3], r11 = P[4], r12 = P[5];
    const float r20 = P[6], r21 = P[7], r22 = P[8];
    const float finv = P[10];

    const float dx = ((float)x - 128.0f) * finv;   // cx = PW/2
    const float dy = ((float)y - 128.0f) * finv;   // cy = PH/2

    const float d0 = r00 * dx + r01 * dy + r02;
    const float d1 = r10 * dx + r11 * dy + r12;
    const float d2 = r20 * dx + r21 * dy + r22;

    const float rn = rsqrtf(d0 * d0 + d1 * d1 + d2 * d2);
    float sa = d2 * rn;                          // clamp: approx can give |.|>1
    sa = fminf(1.0f, fmaxf(-1.0f, sa));
    const float phi = asinf(sa);
    const float theta = atan2f(d1, d0);

    // theta in (-pi, pi] -> raw u in (-4095.5, 0.5]; |raw| < W so fmod == id.
    float ui = (theta - PI_F) * ((float)IW / (2.0f * PI_F)) + 0.5f;
    if (ui < 0.0f) ui += (float)IW;
    // phi in [-pi/2, pi/2] -> raw v in [-2047.5, 0.5].
    float uj = (phi - 0.5f * PI_F) * ((float)IH / PI_F) + 0.5f;
    if (uj < 0.0f) uj += (float)IH;

    const float u0f = floorf(ui);
    const float v0f = floorf(uj);
    const float du = ui - u0f;
    const float dv = uj - v0f;

    int u0 = ((int)u0f) & (IW - 1);     // ui >= 0; handles ui==IW rounding edge too
    int u1 = (u0 + 1) & (IW - 1);
    int v0 = (int)v0f;
    if (v0 < 0) v0 = 0;
    if (v0 > IH - 1) v0 = IH - 1;
    int v1 = v0 + 1;
    if (v1 > IH - 1) v1 = IH - 1;

    const float w00 = (1.0f - du) * (1.0f - dv);
    const float w01 = du * (1.0f - dv);
    const float w10 = (1.0f - du) * dv;
    const float w11 = du * dv;

    const int i00 = v0 * IW + u0;
    const int i01 = v0 * IW + u1;
    const int i10 = v1 * IW + u0;
    const int i11 = v1 * IW + u1;

    float* o = out + ((size_t)(b * 3) * PH + y) * PW + x;
#pragma unroll
    for (int c = 0; c < 3; ++c) {
        const float* ic = img + (size_t)c * (IH * IW);
        float v = ic[i00] * w00 + ic[i01] * w01 + ic[i10] * w10 + ic[i11] * w11;
        o[(size_t)c * PH * PW] = fast_tanh(v);
    }
}

extern "C" void kernel_launch(void* const* d_in, const int* in_sizes, int n_in,
                              void* d_out, int out_size, void* d_ws, size_t ws_size,
                              hipStream_t stream) {
    const float* img   = (const float*)d_in[0];
    const float* fov   = (const float*)d_in[1];
    const float* roll  = (const float*)d_in[2];
    const float* pitch = (const float*)d_in[3];
    const float* yaw   = (const float*)d_in[4];
    float* out = (float*)d_out;

    e2p_kernel<<<NB * PH, 256, 0, stream>>>(img, fov, roll, pitch, yaw, out);
}